// Round 5
// baseline (120.502 us; speedup 1.0000x reference)
//
#include <hip/hip_runtime.h>
#include <hip/hip_bf16.h>

// JointLengthLoss: mean over [B,20] of | ||pred_a-pred_b|| - ||gt_a-gt_b|| | / ||gt_a-gt_b||
// B = 524288, joints [B,21,3] f32.
//
// R4: fix R2's divergent-request bound (64 cache lines per load instr) with
// coalesced reg-staged LDS tiles (T14 async-STAGE split), but with ZERO manual
// sync: global_load_dwordx4 -> regs for tile t+1 issued before ds_write of
// tile t; compiler's vmcnt wait before the ds_write lands after compute(t-1),
// hiding HBM latency. Double-buffered LDS, ONE __syncthreads per tile.
// No inline asm, uniform control flow -> cannot hang.

#define TILE_BYTES   16128          // 64 samples * 63 floats * 4B
#define TILE_PAD_F   4096           // 16 KiB per input per buffer (256B slack for clamped tail)
#define NBLOCKS      512

static constexpr int BA[20] = {3,2,20,8,9,10,20,4,5,6,20,1,0,16,17,18,0,12,13,14};
static constexpr int BB[20] = {2,20,8,9,10,11,4,5,6,7,1,0,16,17,18,19,12,13,14,15};

__global__ __launch_bounds__(256)
void jll_kernel(const float* __restrict__ pred,
                const float* __restrict__ gt,
                float* __restrict__ partials,
                int tiles_per_block) {
    __shared__ __align__(16) float lds[2][2][TILE_PAD_F];   // [buf][input][floats] = 64 KiB
    __shared__ float wsum[4];

    const int tid  = threadIdx.x;
    const int wave = tid >> 6;
    const int lane = tid & 63;

    // ---- per-thread bone tables via branchless constant selects (registers) ----
    const int g = tid & 3;                    // bone group: bones 5g..5g+4
    int ja[5], jb[5];
    #pragma unroll
    for (int k = 0; k < 5; ++k) {
        ja[k] = 3 * ((g == 0) ? BA[k] : (g == 1) ? BA[5 + k] : (g == 2) ? BA[10 + k] : BA[15 + k]);
        jb[k] = 3 * ((g == 0) ? BB[k] : (g == 1) ? BB[5 + k] : (g == 2) ? BB[10 + k] : BB[15 + k]);
    }
    const int smoff = (tid >> 2) * 63;        // this thread's sample base (floats) in LDS

    // ---- per-thread staging offsets ----
    // chunk c covers bytes [(wave*4+c)*1024 + lane*16); tail chunk 15 clamps
    // lanes >=48 into valid range (duplicate loads land in LDS pad, never read).
    int goff[4];   // clamped global/source byte offset within tile
    int doff[4];   // unclamped LDS dest float index (max 16368B < 16384B pad)
    #pragma unroll
    for (int c = 0; c < 4; ++c) {
        const int chunk = wave * 4 + c;
        int o = chunk * 1024 + lane * 16;
        doff[c] = o >> 2;
        if (o > TILE_BYTES - 16) o = TILE_BYTES - 16;
        goff[c] = o;
    }

    const size_t tile0 = (size_t)blockIdx.x * tiles_per_block;

    float4 rp[4], rg[4];

    // ---- prologue: load tile 0 into regs ----
    {
        const char* srcP = (const char*)pred + tile0 * (size_t)TILE_BYTES;
        const char* srcG = (const char*)gt   + tile0 * (size_t)TILE_BYTES;
        #pragma unroll
        for (int c = 0; c < 4; ++c) {
            rp[c] = *reinterpret_cast<const float4*>(srcP + goff[c]);
            rg[c] = *reinterpret_cast<const float4*>(srcG + goff[c]);
        }
    }

    float sum = 0.0f;

    for (int t = 0; t < tiles_per_block; ++t) {
        const int q = t & 1;

        // ---- write staged regs into LDS buf q (compiler waits vmcnt here) ----
        #pragma unroll
        for (int c = 0; c < 4; ++c) {
            *reinterpret_cast<float4*>(&lds[q][0][doff[c]]) = rp[c];
            *reinterpret_cast<float4*>(&lds[q][1][doff[c]]) = rg[c];
        }

        // ---- issue next tile's loads (regs free after ds_write consumed them) ----
        if (t + 1 < tiles_per_block) {
            const size_t nt = tile0 + t + 1;
            const char* srcP = (const char*)pred + nt * (size_t)TILE_BYTES;
            const char* srcG = (const char*)gt   + nt * (size_t)TILE_BYTES;
            #pragma unroll
            for (int c = 0; c < 4; ++c) {
                rp[c] = *reinterpret_cast<const float4*>(srcP + goff[c]);
                rg[c] = *reinterpret_cast<const float4*>(srcG + goff[c]);
            }
        }

        __syncthreads();   // buf q fully written, visible to all

        // ---- compute tile t: 5 bones of sample (tid>>2) from LDS ----
        {
            const float* SP = &lds[q][0][smoff];
            const float* SG = &lds[q][1][smoff];
            #pragma unroll
            for (int k = 0; k < 5; ++k) {
                const int a = ja[k], c = jb[k];
                float dx = SP[a + 0] - SP[c + 0];
                float dy = SP[a + 1] - SP[c + 1];
                float dz = SP[a + 2] - SP[c + 2];
                float pl = sqrtf(dx * dx + dy * dy + dz * dz);
                float ex = SG[a + 0] - SG[c + 0];
                float ey = SG[a + 1] - SG[c + 1];
                float ez = SG[a + 2] - SG[c + 2];
                float gl = sqrtf(ex * ex + ey * ey + ez * ez);
                sum += fabsf(pl - gl) / gl;
            }
        }
        // next iteration writes buf q^1 (no conflict with reads of buf q);
        // buf q is rewritten only at t+2, separated by the t+1 __syncthreads.
    }

    // ---- wave64 shuffle reduction, then cross-wave via LDS ----
    #pragma unroll
    for (int off = 32; off > 0; off >>= 1)
        sum += __shfl_down(sum, off);

    __syncthreads();   // compute reads of last buf done before wsum reuse concerns (paranoia, cheap)
    if (lane == 0) wsum[wave] = sum;
    __syncthreads();
    if (tid == 0)
        partials[blockIdx.x] = wsum[0] + wsum[1] + wsum[2] + wsum[3];
}

__global__ __launch_bounds__(256)
void jll_final_kernel(const float* __restrict__ partials, int nparts,
                      float* __restrict__ out, float inv_count) {
    const int tid = threadIdx.x;
    float sum = 0.0f;
    for (int i = tid; i < nparts; i += 256) sum += partials[i];

    #pragma unroll
    for (int off = 32; off > 0; off >>= 1)
        sum += __shfl_down(sum, off);

    __shared__ float wsum[4];
    const int lane = tid & 63;
    const int wid  = tid >> 6;
    if (lane == 0) wsum[wid] = sum;
    __syncthreads();
    if (tid == 0)
        out[0] = (wsum[0] + wsum[1] + wsum[2] + wsum[3]) * inv_count;
}

extern "C" void kernel_launch(void* const* d_in, const int* in_sizes, int n_in,
                              void* d_out, int out_size, void* d_ws, size_t ws_size,
                              hipStream_t stream) {
    const float* pred = (const float*)d_in[0];
    const float* gt   = (const float*)d_in[1];
    float* out = (float*)d_out;
    float* partials = (float*)d_ws;

    const int nsamples = in_sizes[0] / 63;            // 524288
    const int ntiles   = nsamples / 64;               // 8192
    const int tiles_per_block = ntiles / NBLOCKS;     // 16 (exact)

    jll_kernel<<<NBLOCKS, 256, 0, stream>>>(pred, gt, partials, tiles_per_block);

    const float inv_count = 1.0f / ((float)nsamples * 20.0f);
    jll_final_kernel<<<1, 256, 0, stream>>>(partials, NBLOCKS, out, inv_count);
}

// Round 6
// 49.559 us; speedup vs baseline: 2.4315x; 2.4315x over previous
//
#include <hip/hip_runtime.h>
#include <hip/hip_bf16.h>

// JointLengthLoss: mean over [B,20] of | ||pred_a-pred_b|| - ||gt_a-gt_b|| | / ||gt_a-gt_b||
// B = 524288, joints [B,21,3] f32.
//
// R5 = R3 resubmit (R4 proved the reg-staged variant spills: 207MB HBM writes).
// Coalesced global->LDS staging via global_load_lds (no VGPR round-trip),
// double-buffered with counted vmcnt (never drain to 0 mid-loop): tile t+1's
// 8 loads stay in flight across the barrier while compute(t) runs.
// Audit: vmcnt(8) retires exactly tile t's 8 per-wave loads; buffer reuse is
// fenced by lgkmcnt(0)+s_barrier at loop end; "memory" clobbers order the
// LDS reads (they are memory ops, not register-only); sched_barrier(0) added
// as rule-18 insurance.

#define TILE_BYTES   16128          // 64 samples * 63 floats * 4B
#define TILE_PAD_F   4096           // 16384 B per input per buffer (256B pad for clamped tail)
#define NBLOCKS      512

static constexpr int BA[20] = {3,2,20,8,9,10,20,4,5,6,20,1,0,16,17,18,0,12,13,14};
static constexpr int BB[20] = {2,20,8,9,10,11,4,5,6,7,1,0,16,17,18,19,12,13,14,15};

typedef __attribute__((address_space(1))) const void gvoid_t;
typedef __attribute__((address_space(3))) void lvoid_t;

__global__ __launch_bounds__(256)
void jll_kernel(const float* __restrict__ pred,
                const float* __restrict__ gt,
                float* __restrict__ partials,
                int tiles_per_block) {
    __shared__ __align__(16) float lds[2][2][TILE_PAD_F];   // [buf][input][floats] = 64 KiB
    __shared__ float wsum[4];

    const int tid  = threadIdx.x;
    const int wave = tid >> 6;
    const int lane = tid & 63;

    // ---- per-thread bone tables via branchless constant selects (registers) ----
    const int g = tid & 3;                    // bone group: bones 5g..5g+4
    int ja[5], jb[5];
    #pragma unroll
    for (int k = 0; k < 5; ++k) {
        ja[k] = 3 * ((g == 0) ? BA[k] : (g == 1) ? BA[5 + k] : (g == 2) ? BA[10 + k] : BA[15 + k]);
        jb[k] = 3 * ((g == 0) ? BB[k] : (g == 1) ? BB[5 + k] : (g == 2) ? BB[10 + k] : BB[15 + k]);
    }
    const int smoff = (tid >> 2) * 63;        // this thread's sample base (floats) in LDS

    const size_t tile0 = (size_t)blockIdx.x * tiles_per_block;

    // STAGE: 8 global_load_lds per thread (4 chunks x {pred,gt}).
    // LDS dest: wave-uniform base + lane*16 (HW rule). Global src: per-lane.
    // Tail chunk 15: lanes >=48 clamp to the last valid 16B of the tile;
    // their LDS writes land in the 256B pad (floats 4032..4095, never read).
    auto STAGE = [&](int q, size_t tile) {
        const char* srcP = (const char*)pred + tile * (size_t)TILE_BYTES;
        const char* srcG = (const char*)gt   + tile * (size_t)TILE_BYTES;
        #pragma unroll
        for (int c = 0; c < 4; ++c) {
            const int chunk = wave * 4 + c;
            int off = chunk * 1024 + lane * 16;
            if (off > TILE_BYTES - 16) off = TILE_BYTES - 16;
            __builtin_amdgcn_global_load_lds(
                (gvoid_t*)(srcP + off), (lvoid_t*)&lds[q][0][chunk * 256], 16, 0, 0);
            __builtin_amdgcn_global_load_lds(
                (gvoid_t*)(srcG + off), (lvoid_t*)&lds[q][1][chunk * 256], 16, 0, 0);
        }
    };

    float sum = 0.0f;

    STAGE(0, tile0);                               // prologue: tile 0 -> buf 0 (8 in flight)

    for (int t = 0; t < tiles_per_block; ++t) {
        if (t + 1 < tiles_per_block) {
            STAGE((t + 1) & 1, tile0 + t + 1);     // 8 more in flight (16 total)
            // retire tile t's 8 loads; keep tile t+1's 8 in flight across the barrier
            asm volatile("s_waitcnt vmcnt(8)\n\ts_barrier" ::: "memory");
        } else {
            asm volatile("s_waitcnt vmcnt(0)\n\ts_barrier" ::: "memory");
        }
        __builtin_amdgcn_sched_barrier(0);         // rule-18 insurance: no hoisting past the wait

        // ---- compute tile t from buf[t&1]: 5 bones of sample (tid>>2) ----
        {
            const float* SP = &lds[t & 1][0][smoff];
            const float* SG = &lds[t & 1][1][smoff];
            #pragma unroll
            for (int k = 0; k < 5; ++k) {
                const int a = ja[k], c = jb[k];
                float dx = SP[a + 0] - SP[c + 0];
                float dy = SP[a + 1] - SP[c + 1];
                float dz = SP[a + 2] - SP[c + 2];
                float pl = sqrtf(dx * dx + dy * dy + dz * dz);
                float ex = SG[a + 0] - SG[c + 0];
                float ey = SG[a + 1] - SG[c + 1];
                float ez = SG[a + 2] - SG[c + 2];
                float gl = sqrtf(ex * ex + ey * ey + ez * ez);
                sum += fabsf(pl - gl) / gl;
            }
        }

        // all waves done reading buf[t&1] before iter t+1 issues STAGE into it
        asm volatile("s_waitcnt lgkmcnt(0)\n\ts_barrier" ::: "memory");
    }

    // ---- wave64 shuffle reduction, then cross-wave via LDS ----
    #pragma unroll
    for (int off = 32; off > 0; off >>= 1)
        sum += __shfl_down(sum, off);

    if (lane == 0) wsum[wave] = sum;
    __syncthreads();
    if (tid == 0)
        partials[blockIdx.x] = wsum[0] + wsum[1] + wsum[2] + wsum[3];
}

__global__ __launch_bounds__(256)
void jll_final_kernel(const float* __restrict__ partials, int nparts,
                      float* __restrict__ out, float inv_count) {
    const int tid = threadIdx.x;
    float sum = 0.0f;
    for (int i = tid; i < nparts; i += 256) sum += partials[i];

    #pragma unroll
    for (int off = 32; off > 0; off >>= 1)
        sum += __shfl_down(sum, off);

    __shared__ float wsum[4];
    const int lane = tid & 63;
    const int wid  = tid >> 6;
    if (lane == 0) wsum[wid] = sum;
    __syncthreads();
    if (tid == 0)
        out[0] = (wsum[0] + wsum[1] + wsum[2] + wsum[3]) * inv_count;
}

extern "C" void kernel_launch(void* const* d_in, const int* in_sizes, int n_in,
                              void* d_out, int out_size, void* d_ws, size_t ws_size,
                              hipStream_t stream) {
    const float* pred = (const float*)d_in[0];
    const float* gt   = (const float*)d_in[1];
    float* out = (float*)d_out;
    float* partials = (float*)d_ws;

    const int nsamples = in_sizes[0] / 63;            // 524288
    const int ntiles   = nsamples / 64;               // 8192
    const int tiles_per_block = ntiles / NBLOCKS;     // 16 (exact)

    jll_kernel<<<NBLOCKS, 256, 0, stream>>>(pred, gt, partials, tiles_per_block);

    const float inv_count = 1.0f / ((float)nsamples * 20.0f);
    jll_final_kernel<<<1, 256, 0, stream>>>(partials, NBLOCKS, out, inv_count);
}